// Round 1
// baseline (343.741 us; speedup 1.0000x reference)
//
#include <hip/hip_runtime.h>
#include <hip/hip_fp16.h>

typedef _Float16 f16x8 __attribute__((ext_vector_type(8)));
typedef float    f32x4 __attribute__((ext_vector_type(4)));

#define TILE   16
#define HALO   22      // TILE + 6
#define KK     7
#define NCLASS 49
#define IMW    256
#define IMH    256
#define HW     65536   // 256*256
#define HH     484     // HALO*HALO
#define NV     42      // V-rows 0..41 (n00 <= 40)
#define WHST   52      // W row stride in HALVES (104 B -> 8B-aligned rows)

// LDS layout (dwords), total 13415 -> 53660 B -> 3 blocks/CU (was 2):
#define OFF_OMV    0        // [2][42][128] packed half2 (om[v], om[v+7]) = 10752
#define OFF_HALOF  10752    // uint[484]  (fy,fx) half2                  =   484
#define OFF_HALOB  11236    // u8  [484]  n00*4 (255 = OOB)              =   121
#define OFF_KV     11357    // uint[49*42] vertical K pairs              =  2058
#define SH_TOTAL   13415
// overlays (lifetime-disjoint):
//   iml64 float2[484] @10752, iml32 float[484] @11720  (halo/KV dead after P3)
//   Whf   __half[256*52]  @0                           (omV dead after P4)
#define OFF_IML64  10752
#define OFF_IML32  11720

__device__ __forceinline__ unsigned h2u(__half2 h) { union { __half2 h; unsigned u; } c; c.h = h; return c.u; }
__device__ __forceinline__ __half2  u2h(unsigned u) { union { __half2 h; unsigned u; } c; c.u = u; return c.h; }

__global__ __launch_bounds__(256, 3)
void gtnet_kernel(const float* __restrict__ im_input,
                  const float* __restrict__ gt_motion,
                  const float* __restrict__ m_kernel,
                  float* __restrict__ out_pred,
                  float* __restrict__ out_mask)
{
    __shared__ __align__(16) unsigned SH[SH_TOTAL];
    unsigned*      const omV    = SH + OFF_OMV;
    unsigned*      const haloF  = SH + OFF_HALOF;
    unsigned char* const haloB8 = (unsigned char*)(SH + OFF_HALOB);
    unsigned*      const KV     = SH + OFF_KV;     // KV[s*42+n] = (K[n,s], K[n+7,s]) f16x2
    float2*        const iml64  = (float2*)(SH + OFF_IML64);
    float*         const iml32  = (float*)(SH + OFF_IML32);
    __half*        const Whf    = (__half*)SH;     // f16 W, overlays omV after P4

    const int tid  = threadIdx.x;
    const int lane = tid & 63, wv_id = tid >> 6;
    const int tx = tid & 15, ty = tid >> 4;
    const int x0 = blockIdx.x * TILE, y0 = blockIdx.y * TILE;
    const int b  = blockIdx.z;
    const int x = x0 + tx, y = y0 + ty;

    const float* mot_x = gt_motion + (size_t)b * 2 * HW;  // channel 0 -> ax
    const float* mot_y = mot_x + HW;                      // channel 1 -> ay
    const float* imP   = im_input + ((size_t)b * 6 + 3) * HW;  // last 3 channels

    // ---------------- phase 0: im halo -> REGISTERS (LDS write deferred) -------
    float2 imr01[2]; float imr2[2];
    #pragma unroll
    for (int k = 0; k < 2; k++) {
        int i = tid + k * 256;
        float2 v01 = make_float2(0.0f, 0.0f); float v2 = 0.0f;
        if (i < HH) {
            int hy = i / HALO, hx = i - hy * HALO;
            int gy = y0 - 3 + hy, gx = x0 - 3 + hx;
            if (gy >= 0 && gy < IMH && gx >= 0 && gx < IMW) {
                int off = gy * IMW + gx;
                v01.x = imP[off];
                v01.y = imP[off + HW];
                v2    = imP[off + 2 * HW];
            }
        }
        imr01[k] = v01; imr2[k] = v2;
    }

    // ---------------- phase 1: staging ----------------
    for (int i = tid; i < NCLASS * NV; i += 256) {      // KV
        int s = i / NV, n = i - s * NV;
        float k0 = m_kernel[n * NCLASS + s];
        float k7 = m_kernel[(n + KK) * NCLASS + s];     // n <= 41 -> n+7 <= 48
        KV[i] = h2u(__halves2half2(__float2half_rn(k0), __float2half_rn(k7)));
    }
    #pragma unroll
    for (int k = 0; k < 2; k++) {                       // packed motion halo
        int i = tid + k * 256;
        if (i < HH) {
            int hy = i / HALO, hx = i - hy * HALO;
            int gy = y0 - 3 + hy, gx = x0 - 3 + hx;
            unsigned pf = 0u, n4b = 255u;               // 255 = OOB sentinel
            if (gy >= 0 && gy < IMH && gx >= 0 && gx < IMW) {
                int off = gy * IMW + gx;
                float ay = mot_y[off] + 3.0f;
                float ax = mot_x[off] + 3.0f;
                float iyf = floorf(ay), ixf = floorf(ax);
                float fy = ay - iyf,    fx = ax - ixf;
                int n00 = (int)iyf * KK + (int)ixf;
                n00 = (n00 < 0) ? 0 : ((n00 > 40) ? 40 : n00);
                pf  = h2u(__halves2half2(__float2half_rn(fy), __float2half_rn(fx)));
                n4b = (unsigned)(n00 * 4);
            }
            haloF[i]  = pf;
            haloB8[i] = (unsigned char)n4b;
        }
    }
    {   // zero omV (10752 dwords) via b128
        uint4* p = reinterpret_cast<uint4*>(omV);
        for (int i = tid; i < (2 * NV * 128) / 4; i += 256) p[i] = make_uint4(0, 0, 0, 0);
    }

    __syncthreads();

    // ---------------- phase 2: m_mask dense write (exact f32) ----------------
    {
        int off = y * IMW + x;
        float ay = mot_y[off] + 3.0f;
        float ax = mot_x[off] + 3.0f;
        float iyf = floorf(ay), ixf = floorf(ax);
        float fy = ay - iyf,    fx = ax - ixf;
        int   iy = (int)iyf,    ix = (int)ixf;
        float wyA[KK], wxB[KK];
        #pragma unroll
        for (int a = 0; a < KK; a++) {
            wyA[a] = (a == iy) ? (1.0f - fy) : ((a == iy + 1) ? fy : 0.0f);
            wxB[a] = (a == ix) ? (1.0f - fx) : ((a == ix + 1) ? fx : 0.0f);
        }
        float* mm = out_mask + (size_t)b * NCLASS * HW + off;
        #pragma unroll
        for (int a = 0; a < KK; a++)
            #pragma unroll
            for (int bb = 0; bb < KK; bb++)
                mm[(size_t)(a * KK + bb) * HW] = wyA[a] * wxB[bb];
    }

    // ---------------- phase 3: scatter — b32 + u8 + read2 + read2 + write2 -----
    unsigned* const omHalf = omV + (tid >> 7) * (NV * 128) + (tid & 127);
    const __half hone = __float2half_rn(1.0f);
    #pragma unroll
    for (int u = 0; u < KK; u++) {
        #pragma unroll
        for (int v = 0; v < KK; v++) {
            const int s = u * KK + v;                    // compile-time
            const int q = (ty + u) * HALO + (tx + v);
            unsigned pf  = haloF[q];                     // ds_read_b32
            unsigned n4u = (unsigned)haloB8[q];          // ds_read_u8
            unsigned n4  = (n4u == 255u) ? 0u : n4u;
            __half2 f2 = u2h(pf);
            __half fy = __low2half(f2), fx = __high2half(f2);
            unsigned wyb = h2u(__halves2half2(__hsub(hone, fy), fy));
            wyb = (n4u == 255u) ? 0u : wyb;              // OOB -> wy = 0 -> zero taps
            __half2 wy  = u2h(wyb);
            __half2 wxl = __half2half2(__hsub(hone, fx));
            __half2 wxh = __half2half2(fx);
            const unsigned* kp =
                (const unsigned*)((const char*)KV + s * (NV * 4) + n4);
            unsigned kvA = kp[0], kvB = kp[1];           // ds_read2_b32 (0,1)
            unsigned* ob = (unsigned*)((char*)omHalf + n4 * 128);  // n00*512 B
            unsigned o0 = ob[0], o1 = ob[128];           // ds_read2_b32 (0,128)
            __half2 cA = __hmul2(__hmul2(wy, wxl), u2h(kvA));
            __half2 cB = __hmul2(__hmul2(wy, wxh), u2h(kvB));
            ob[0]   = h2u(__hadd2(u2h(o0), cA));         // ds_write2_b32 (0,128)
            ob[128] = h2u(__hadd2(u2h(o1), cB));
        }
    }

    __syncthreads();   // omV complete; haloF/haloB/KV now dead

    // ---------------- phase 3.5: im registers -> LDS (overlay dead region) -----
    #pragma unroll
    for (int k = 0; k < 2; k++) {
        int i = tid + k * 256;
        if (i < HH) { iml64[i] = imr01[k]; iml32[i] = imr2[k]; }
    }

    // ---------------- phase 4a: B fragments straight from global m_kernel ------
    // (replaces LDS KE; 9.6 KB table is L1/L2-hot, same 32 VGPRs as before)
    f16x8 bfr[2][4];
    #pragma unroll
    for (int kit = 0; kit < 2; kit++) {
        #pragma unroll
        for (int nt = 0; nt < 4; nt++) {
            int t  = nt * 16 + (lane & 15);
            int tc = (t > 48) ? 48 : t;                  // t>=49 cols are discarded
            int k0 = kit * 32 + (lane >> 4) * 8;
            union { unsigned u[4]; f16x8 v; } bu;
            #pragma unroll
            for (int j = 0; j < 4; j++) {
                int c0 = k0 + 2 * j;
                float lo = (c0 <= 48) ? m_kernel[c0 * NCLASS + tc]       : 0.0f;
                float hi = (c0 <= 47) ? m_kernel[(c0 + 1) * NCLASS + tc] : 0.0f;
                bu.u[j] = h2u(__halves2half2(__float2half_rn(lo), __float2half_rn(hi)));
            }
            bfr[kit][nt] = bu.v;
        }
    }

    // ---------------- phase 4b: assemble MFMA f16 A fragments ------------------
    // om[n] = lo(V[n]) + hi(V[n-7]).  A dword covers classes (c0, c0+1), c0 even.
    f16x8 af[2][4];
    #pragma unroll
    for (int kit = 0; kit < 2; kit++) {
        #pragma unroll
        for (int mt = 0; mt < 4; mt++) {
            int k0  = kit * 32 + (lane >> 4) * 8;
            int px  = wv_id * 64 + mt * 16 + (lane & 15);
            const unsigned* pxb = omV + (px >> 7) * (NV * 128) + (px & 127);
            union { unsigned u[4]; f16x8 v; } au;
            #pragma unroll
            for (int j = 0; j < 4; j++) {
                int c0 = k0 + 2 * j;                     // even
                int rl = (c0 > 40) ? 40 : c0;
                unsigned d0 = pxb[rl * 128], d1 = pxb[rl * 128 + 128];  // read2
                unsigned loM = (d0 & 0xffffu) | (d1 << 16);
                loM = (c0 <= 40) ? loM : 0u;
                int r0 = c0 - 7; r0 = (r0 < 0) ? 0 : ((r0 > 41) ? 41 : r0);
                int r1 = c0 - 6; r1 = (r1 < 0) ? 0 : ((r1 > 41) ? 41 : r1);
                unsigned e0 = pxb[r0 * 128];
                unsigned e1 = pxb[r1 * 128];
                e0 = (c0 >= 8 && c0 <= 48) ? e0 : 0u;
                e1 = (c0 >= 6 && c0 <= 48) ? e1 : 0u;
                unsigned hiM = (e0 >> 16) | (e1 & 0xffff0000u);
                au.u[j] = h2u(__hadd2(u2h(loM), u2h(hiM)));
            }
            af[kit][mt] = au.v;
        }
    }

    __syncthreads();   // omV reads done before Whf overwrites the region

    // ---------------- phase 5: MFMA GEMM  W[256x49] = om x K^T -----------------
    f32x4 acc[4][4];
    #pragma unroll
    for (int mt = 0; mt < 4; mt++) {
        #pragma unroll
        for (int nt = 0; nt < 4; nt++) {
            f32x4 c = {0.0f, 0.0f, 0.0f, 0.0f};
            c = __builtin_amdgcn_mfma_f32_16x16x32_f16(af[0][mt], bfr[0][nt], c, 0, 0, 0);
            c = __builtin_amdgcn_mfma_f32_16x16x32_f16(af[1][mt], bfr[1][nt], c, 0, 0, 0);
            acc[mt][nt] = c;
        }
    }

    // C/D layout: col=lane&15 (t), row=(lane>>4)*4+reg (px) -> Whf[px*52+t] (f16)
    #pragma unroll
    for (int mt = 0; mt < 4; mt++) {
        #pragma unroll
        for (int nt = 0; nt < 4; nt++) {
            int t = nt * 16 + (lane & 15);
            if (t < NCLASS) {
                #pragma unroll
                for (int r = 0; r < 4; r++) {
                    int px = wv_id * 64 + mt * 16 + (lane >> 4) * 4 + r;
                    Whf[px * WHST + t] = __float2half_rn(acc[mt][nt][r]);
                }
            }
        }
    }

    __syncthreads();   // W complete; iml writes also ordered before here

    // ---------------- phase 6: apply effective 7x7 kernel ----------------------
    union { uint2 v[13]; __half h[52]; } wr;             // 13 x ds_read_b64
    const uint2* wp = (const uint2*)(Whf + tid * WHST);  // 104B stride, 8B aligned
    #pragma unroll
    for (int c = 0; c < 13; c++) wr.v[c] = wp[c];

    float a0 = 0.0f, a1 = 0.0f, a2 = 0.0f;
    #pragma unroll
    for (int p = 0; p < KK; p++) {
        #pragma unroll
        for (int qq = 0; qq < KK; qq++) {
            float wvv = __half2float(wr.h[p * KK + qq]); // static index -> regs
            int   hq  = (ty + p) * HALO + (tx + qq);
            float2 i01 = iml64[hq];                      // ds_read_b64
            float  i2  = iml32[hq];                      // ds_read_b32
            a0 = fmaf(wvv, i01.x, a0);
            a1 = fmaf(wvv, i01.y, a1);
            a2 = fmaf(wvv, i2,    a2);
        }
    }
    float* pr = out_pred + (size_t)b * 3 * HW + y * IMW + x;
    pr[0]      = a0;
    pr[HW]     = a1;
    pr[2 * HW] = a2;
}

extern "C" void kernel_launch(void* const* d_in, const int* in_sizes, int n_in,
                              void* d_out, int out_size, void* d_ws, size_t ws_size,
                              hipStream_t stream) {
    const float* im_input  = (const float*)d_in[0];
    // d_in[1] = im_output: unused by the reference computation
    const float* gt_motion = (const float*)d_in[2];
    const float* m_kernel  = (const float*)d_in[3];

    float* pred = (float*)d_out;                        // (16,3,256,256)
    float* mask = pred + (size_t)16 * 3 * HW;           // (16,49,256,256)

    dim3 grid(IMW / TILE, IMH / TILE, 16);
    dim3 block(256);
    hipLaunchKernelGGL(gtnet_kernel, grid, block, 0, stream,
                       im_input, gt_motion, m_kernel, pred, mask);
}

// Round 3
// 336.666 us; speedup vs baseline: 1.0210x; 1.0210x over previous
//
#include <hip/hip_runtime.h>
#include <hip/hip_fp16.h>

typedef _Float16 f16x8 __attribute__((ext_vector_type(8)));
typedef float    f32x4 __attribute__((ext_vector_type(4)));

#define TILE   16
#define HALO   22      // TILE + 6
#define KK     7
#define NCLASS 49
#define IMW    256
#define IMH    256
#define HW     65536   // 256*256
#define HH     484     // HALO*HALO
#define NV     42      // V-rows 0..41 (n00 <= 40)
#define WROW   34      // W row stride in DWORDS (8B-aligned, write-banks 2-way)

// LDS layout (dwords), total 13415 -> 53660 B -> 3 blocks/CU:
#define OFF_OMV    0        // [2][42][128] packed half2 (V[v].lo, V[v].hi) = 10752
#define OFF_HALOF  10752    // uint[484]  (fy,fx) half2                    =   484
#define OFF_HALOB  11236    // u8  [484]  n00*4 (255 = OOB)                =   121
#define OFF_KV     11357    // uint[49*42] vertical K pairs                =  2058
#define SH_TOTAL   13415
// overlays (lifetime-disjoint):
//   iml64 float2[484] @10752, iml32 float[484] @11720  (halo/KV dead after P3)
//   W     uint[256*34] @0  rows: dw d in [0,16): (t=d, t=d+16);
//                          dw 16+d: (t=32+d, t=48+d)   (omV dead after P4 reads)
#define OFF_IML64  10752
#define OFF_IML32  11720

__device__ __forceinline__ unsigned h2u(__half2 h) { union { __half2 h; unsigned u; } c; c.h = h; return c.u; }
__device__ __forceinline__ __half2  u2h(unsigned u) { union { __half2 h; unsigned u; } c; c.u = u; return c.h; }

__global__ __launch_bounds__(256, 3)
void gtnet_kernel(const float* __restrict__ im_input,
                  const float* __restrict__ gt_motion,
                  const float* __restrict__ m_kernel,
                  float* __restrict__ out_pred,
                  float* __restrict__ out_mask)
{
    __shared__ __align__(16) unsigned SH[SH_TOTAL];
    unsigned*      const omV    = SH + OFF_OMV;
    unsigned*      const haloF  = SH + OFF_HALOF;
    unsigned char* const haloB8 = (unsigned char*)(SH + OFF_HALOB);
    unsigned*      const KV     = SH + OFF_KV;     // KV[s*42+n] = (K[n,s], K[n+7,s]) f16x2
    float2*        const iml64  = (float2*)(SH + OFF_IML64);
    float*         const iml32  = (float*)(SH + OFF_IML32);

    const int tid  = threadIdx.x;
    const int lane = tid & 63, wv_id = tid >> 6;
    const int tx = tid & 15, ty = tid >> 4;
    const int x0 = blockIdx.x * TILE, y0 = blockIdx.y * TILE;
    const int b  = blockIdx.z;
    const int x = x0 + tx, y = y0 + ty;

    const float* mot_x = gt_motion + (size_t)b * 2 * HW;  // channel 0 -> ax
    const float* mot_y = mot_x + HW;                      // channel 1 -> ay
    const float* imP   = im_input + ((size_t)b * 6 + 3) * HW;  // last 3 channels

    // ---------------- phase 0: im halo -> REGISTERS (LDS write deferred) -------
    float2 imr01[2]; float imr2[2];
    #pragma unroll
    for (int k = 0; k < 2; k++) {
        int i = tid + k * 256;
        float2 v01 = make_float2(0.0f, 0.0f); float v2 = 0.0f;
        if (i < HH) {
            int hy = i / HALO, hx = i - hy * HALO;
            int gy = y0 - 3 + hy, gx = x0 - 3 + hx;
            if (gy >= 0 && gy < IMH && gx >= 0 && gx < IMW) {
                int off = gy * IMW + gx;
                v01.x = imP[off];
                v01.y = imP[off + HW];
                v2    = imP[off + 2 * HW];
            }
        }
        imr01[k] = v01; imr2[k] = v2;
    }

    // ---------------- phase 1: staging ----------------
    for (int i = tid; i < NCLASS * NV; i += 256) {      // KV
        int s = i / NV, n = i - s * NV;
        float k0 = m_kernel[n * NCLASS + s];
        float k7 = m_kernel[(n + KK) * NCLASS + s];     // n <= 41 -> n+7 <= 48
        KV[i] = h2u(__halves2half2(__float2half_rn(k0), __float2half_rn(k7)));
    }
    #pragma unroll
    for (int k = 0; k < 2; k++) {                       // packed motion halo
        int i = tid + k * 256;
        if (i < HH) {
            int hy = i / HALO, hx = i - hy * HALO;
            int gy = y0 - 3 + hy, gx = x0 - 3 + hx;
            unsigned pf = 0u, n4b = 255u;               // 255 = OOB sentinel
            if (gy >= 0 && gy < IMH && gx >= 0 && gx < IMW) {
                int off = gy * IMW + gx;
                float ay = mot_y[off] + 3.0f;
                float ax = mot_x[off] + 3.0f;
                float iyf = floorf(ay), ixf = floorf(ax);
                float fy = ay - iyf,    fx = ax - ixf;
                int n00 = (int)iyf * KK + (int)ixf;
                n00 = (n00 < 0) ? 0 : ((n00 > 40) ? 40 : n00);
                pf  = h2u(__halves2half2(__float2half_rn(fy), __float2half_rn(fx)));
                n4b = (unsigned)(n00 * 4);
            }
            haloF[i]  = pf;
            haloB8[i] = (unsigned char)n4b;
        }
    }
    {   // zero omV (10752 dwords) via b128
        uint4* p = reinterpret_cast<uint4*>(omV);
        for (int i = tid; i < (2 * NV * 128) / 4; i += 256) p[i] = make_uint4(0, 0, 0, 0);
    }

    __syncthreads();

    // ---------------- phase 2: m_mask dense write (exact f32) ----------------
    {
        int off = y * IMW + x;
        float ay = mot_y[off] + 3.0f;
        float ax = mot_x[off] + 3.0f;
        float iyf = floorf(ay), ixf = floorf(ax);
        float fy = ay - iyf,    fx = ax - ixf;
        int   iy = (int)iyf,    ix = (int)ixf;
        float wyA[KK], wxB[KK];
        #pragma unroll
        for (int a = 0; a < KK; a++) {
            wyA[a] = (a == iy) ? (1.0f - fy) : ((a == iy + 1) ? fy : 0.0f);
            wxB[a] = (a == ix) ? (1.0f - fx) : ((a == ix + 1) ? fx : 0.0f);
        }
        float* mm = out_mask + (size_t)b * NCLASS * HW + off;
        #pragma unroll
        for (int a = 0; a < KK; a++)
            #pragma unroll
            for (int bb = 0; bb < KK; bb++)
                mm[(size_t)(a * KK + bb) * HW] = wyA[a] * wxB[bb];
    }

    // ---------------- phase 3: scatter — b32 + u8 + KV read2 + om read2/write2 -
    // thread-private om column (px = tid&127, half = tid>>7): no cross-thread
    // collisions; per-thread RMW ordering is guaranteed by in-order DS issue.
    unsigned* const omHalf = omV + (tid >> 7) * (NV * 128) + (tid & 127);
    const __half hone = __float2half_rn(1.0f);
    #pragma unroll
    for (int u = 0; u < KK; u++) {
        #pragma unroll
        for (int v = 0; v < KK; v++) {
            const int s = u * KK + v;                    // compile-time
            const int q = (ty + u) * HALO + (tx + v);
            unsigned pf  = haloF[q];                     // ds_read_b32 (read2-merged)
            unsigned n4u = (unsigned)haloB8[q];          // ds_read_u8
            unsigned n4  = (n4u == 255u) ? 0u : n4u;
            __half2 f2 = u2h(pf);
            __half fy = __low2half(f2), fx = __high2half(f2);
            unsigned wyb = h2u(__halves2half2(__hsub(hone, fy), fy));
            wyb = (n4u == 255u) ? 0u : wyb;              // OOB -> wy = 0 -> zero taps
            __half2 wy  = u2h(wyb);
            __half2 wxl = __half2half2(__hsub(hone, fx));
            __half2 wxh = __half2half2(fx);
            const unsigned* kp =
                (const unsigned*)((const char*)KV + s * (NV * 4) + n4);
            unsigned kvA = kp[0], kvB = kp[1];           // ds_read2_b32 (0,1)
            unsigned* ob = (unsigned*)((char*)omHalf + n4 * 128);  // n00*512 B
            unsigned o0 = ob[0], o1 = ob[128];           // ds_read2_b32 (0,128)
            __half2 cA = __hmul2(__hmul2(wy, wxl), u2h(kvA));
            __half2 cB = __hmul2(__hmul2(wy, wxh), u2h(kvB));
            ob[0]   = h2u(__hadd2(u2h(o0), cA));         // ds_write2_b32 (0,128)
            ob[128] = h2u(__hadd2(u2h(o1), cB));
        }
    }

    __syncthreads();   // omV complete; haloF/haloB/KV now dead

    // ---------------- phase 3.5: im registers -> LDS (overlay dead region) -----
    #pragma unroll
    for (int k = 0; k < 2; k++) {
        int i = tid + k * 256;
        if (i < HH) { iml64[i] = imr01[k]; iml32[i] = imr2[k]; }
    }

    // ---------------- phase 4+5: K=96 MFMA GEMM, A = V dwords DIRECT -----------
    // Linearity fold: W[px][t] = sum_v loV[v]*K[v][t] + hiV[v]*K[v+7][t]
    // A dword j at kit = omV dword V[kit*16 + (lane>>4)*4 + j][px]  (zero v>41)
    // B dword j        = (K[v][t], K[v+7][t])  built from global (L1-hot, VMEM)
    f32x4 acc[4][4];
    #pragma unroll
    for (int mt = 0; mt < 4; mt++)
        #pragma unroll
        for (int nt = 0; nt < 4; nt++)
            acc[mt][nt] = (f32x4){0.0f, 0.0f, 0.0f, 0.0f};

    const int vb0  = (lane >> 4) * 4;
    const int tcol = lane & 15;
    #pragma unroll
    for (int kit = 0; kit < 3; kit++) {
        f16x8 afk[4];
        #pragma unroll
        for (int mt = 0; mt < 4; mt++) {
            int px = wv_id * 64 + mt * 16 + tcol;
            const unsigned* pxb = omV + (px >> 7) * (NV * 128) + (px & 127);
            int vb = kit * 16 + vb0;
            union { unsigned u[4]; f16x8 v; } au;
            #pragma unroll
            for (int j = 0; j < 4; j++) {
                unsigned d = pxb[(vb + j) * 128];        // ds_read2-mergeable
                au.u[j] = (vb + j <= 41) ? d : 0u;       // in-bounds garbage masked
            }
            afk[mt] = au.v;
        }
        f16x8 bfk[4];
        #pragma unroll
        for (int nt = 0; nt < 4; nt++) {
            int t  = nt * 16 + tcol;
            int tc = (t > 48) ? 48 : t;                  // t>=49 cols are discarded
            union { unsigned u[4]; f16x8 v; } bu;
            #pragma unroll
            for (int j = 0; j < 4; j++) {
                int v = kit * 16 + vb0 + j;
                float lo = (v <= 41) ? m_kernel[v * NCLASS + tc]        : 0.0f;
                float hi = (v <= 41) ? m_kernel[(v + KK) * NCLASS + tc] : 0.0f;
                bu.u[j] = h2u(__halves2half2(__float2half_rn(lo), __float2half_rn(hi)));
            }
            bfk[nt] = bu.v;
        }
        #pragma unroll
        for (int mt = 0; mt < 4; mt++)
            #pragma unroll
            for (int nt = 0; nt < 4; nt++)
                acc[mt][nt] = __builtin_amdgcn_mfma_f32_16x16x32_f16(afk[mt], bfk[nt], acc[mt][nt], 0, 0, 0);
    }

    __syncthreads();   // all omV reads done before W overwrites the region

    // ---------------- phase 5b: packed W write (16 x ds_write2_b32) ------------
    // C/D layout: col=lane&15 (t0), row=(lane>>4)*4+reg (px)
    // dword t0 of row px = (t0, t0+16); dword 16+t0 = (t0+32, t0+48)
    #pragma unroll
    for (int mt = 0; mt < 4; mt++) {
        #pragma unroll
        for (int r = 0; r < 4; r++) {
            int px = wv_id * 64 + mt * 16 + (lane >> 4) * 4 + r;
            unsigned* wrow = SH + px * WROW + tcol;
            unsigned v0 = h2u(__halves2half2(__float2half_rn(acc[mt][0][r]),
                                             __float2half_rn(acc[mt][1][r])));
            unsigned v1 = h2u(__halves2half2(__float2half_rn(acc[mt][2][r]),
                                             __float2half_rn(acc[mt][3][r])));
            wrow[0]  = v0;                               // ds_write2_b32 (0,16)
            wrow[16] = v1;
        }
    }

    __syncthreads();   // W complete; iml writes also ordered before here

    // ---------------- phase 6: apply effective 7x7 kernel ----------------------
    union { uint2 q[16]; unsigned d[32]; } wr;           // 16 x b64 (read2-merged)
    const uint2* wp = (const uint2*)(SH + tid * WROW);   // 136B stride, 8B aligned
    #pragma unroll
    for (int c = 0; c < 16; c++) wr.q[c] = wp[c];

    // static half extraction per t
    #define WHALF(t) ( (t) < 16 ? __low2half(u2h(wr.d[(t)])) :           \
                       (t) < 32 ? __high2half(u2h(wr.d[(t) - 16])) :     \
                       (t) < 48 ? __low2half(u2h(wr.d[(t) - 16])) :      \
                                  __high2half(u2h(wr.d[16])) )

    float a0 = 0.0f, a1 = 0.0f, a2 = 0.0f;
    #pragma unroll
    for (int p = 0; p < KK; p++) {
        #pragma unroll
        for (int qq = 0; qq < KK; qq++) {
            float wvv = __half2float(WHALF(p * KK + qq));
            int   hq  = (ty + p) * HALO + (tx + qq);
            float2 i01 = iml64[hq];                      // ds_read_b64
            float  i2  = iml32[hq];                      // ds_read_b32
            a0 = fmaf(wvv, i01.x, a0);
            a1 = fmaf(wvv, i01.y, a1);
            a2 = fmaf(wvv, i2,    a2);
        }
    }
    #undef WHALF
    float* pr = out_pred + (size_t)b * 3 * HW + y * IMW + x;
    pr[0]      = a0;
    pr[HW]     = a1;
    pr[2 * HW] = a2;
}

extern "C" void kernel_launch(void* const* d_in, const int* in_sizes, int n_in,
                              void* d_out, int out_size, void* d_ws, size_t ws_size,
                              hipStream_t stream) {
    const float* im_input  = (const float*)d_in[0];
    // d_in[1] = im_output: unused by the reference computation
    const float* gt_motion = (const float*)d_in[2];
    const float* m_kernel  = (const float*)d_in[3];

    float* pred = (float*)d_out;                        // (16,3,256,256)
    float* mask = pred + (size_t)16 * 3 * HW;           // (16,49,256,256)

    dim3 grid(IMW / TILE, IMH / TILE, 16);
    dim3 block(256);
    hipLaunchKernelGGL(gtnet_kernel, grid, block, 0, stream,
                       im_input, gt_motion, m_kernel, pred, mask);
}

// Round 4
// 329.263 us; speedup vs baseline: 1.0440x; 1.0225x over previous
//
#include <hip/hip_runtime.h>
#include <hip/hip_fp16.h>

typedef _Float16 f16x8 __attribute__((ext_vector_type(8)));
typedef float    f32x4 __attribute__((ext_vector_type(4)));

#define TILE   16
#define HALO   22      // TILE + 6
#define KK     7
#define NCLASS 49
#define IMW    256
#define IMH    256
#define HW     65536   // 256*256
#define HH     484     // HALO*HALO
#define NV     42      // V-rows 0..41 (n00 <= 40)
#define WROW   34      // W row stride in DWORDS (8B-aligned)

// LDS layout (dwords), total 13424 -> 53696 B -> 3 blocks/CU:
#define OFF_OMV    0        // [2][42][128] packed half2 (V[v].lo, V[v].hi) = 10752
#define OFF_HALOF  10752    // uint[484]  (fy,fx) half2                    =   484
#define OFF_HALOB  11236    // u8  [484]  n00*4 (255 = OOB), pad to       =   124
#define OFF_KV     11360    // uint[49*42 + pad] vertical K pairs (16B al) =  2064
#define SH_TOTAL   13424
// overlays (lifetime-disjoint):
//   iml64 float2[484] @10752, iml32 float[484] @11720  (halo/KV dead after P3)
//   W     uint[256*34] @0                               (omV dead after P4 reads)
#define OFF_IML64  10752
#define OFF_IML32  11720

// workspace layout (dwords): B-frag table [3][4][64] uint4 = 3072 dw; KV = 2064 dw
#define WS_B    0
#define WS_KV   3072
#define WS_KV4  (3072/4)

__device__ __forceinline__ unsigned h2u(__half2 h) { union { __half2 h; unsigned u; } c; c.h = h; return c.u; }
__device__ __forceinline__ __half2  u2h(unsigned u) { union { __half2 h; unsigned u; } c; c.u = u; return c.h; }

// ---------------- setup: precompute f16 tables once per dispatch ---------------
__global__ void gtnet_setup(const float* __restrict__ m_kernel, unsigned* __restrict__ ws)
{
    const int tid = threadIdx.x;
    // B-fragment table: idx = (kit*4+nt)*64 + lane; uint4 = 4 K-dwords j=0..3
    for (int idx = tid; idx < 768; idx += 256) {
        int lane = idx & 63, kitnt = idx >> 6;
        int kit = kitnt >> 2, nt = kitnt & 3;
        int vb0 = (lane >> 4) * 4, tcol = lane & 15;
        int t = nt * 16 + tcol; int tc = (t > 48) ? 48 : t;
        uint4 o;
        unsigned* op = (unsigned*)&o;
        #pragma unroll
        for (int j = 0; j < 4; j++) {
            int v = kit * 16 + vb0 + j;
            float lo = (v <= 41) ? m_kernel[v * NCLASS + tc]        : 0.0f;
            float hi = (v <= 41) ? m_kernel[(v + KK) * NCLASS + tc] : 0.0f;
            op[j] = h2u(__halves2half2(__float2half_rn(lo), __float2half_rn(hi)));
        }
        ((uint4*)ws)[idx] = o;
    }
    // KV table: KV[s*42+n] = (K[n,s], K[n+7,s]) f16x2, padded to 2064 dwords
    for (int i = tid; i < 2064; i += 256) {
        unsigned val = 0u;
        if (i < NCLASS * NV) {
            int s = i / NV, n = i - s * NV;
            val = h2u(__halves2half2(__float2half_rn(m_kernel[n * NCLASS + s]),
                                     __float2half_rn(m_kernel[(n + KK) * NCLASS + s])));
        }
        ws[WS_KV + i] = val;
    }
}

__global__ __launch_bounds__(256, 3)
void gtnet_kernel(const float* __restrict__ im_input,
                  const float* __restrict__ gt_motion,
                  float* __restrict__ out_pred,
                  float* __restrict__ out_mask,
                  const unsigned* __restrict__ ws)
{
    __shared__ __align__(16) unsigned SH[SH_TOTAL];
    unsigned*      const omV    = SH + OFF_OMV;
    unsigned*      const haloF  = SH + OFF_HALOF;
    unsigned char* const haloB8 = (unsigned char*)(SH + OFF_HALOB);
    unsigned*      const KV     = SH + OFF_KV;     // KV[s*42+n] = (K[n,s], K[n+7,s])
    float2*        const iml64  = (float2*)(SH + OFF_IML64);
    float*         const iml32  = (float*)(SH + OFF_IML32);

    const int tid  = threadIdx.x;
    const int lane = tid & 63, wv_id = tid >> 6;
    const int tx = tid & 15, ty = tid >> 4;
    const int x0 = blockIdx.x * TILE, y0 = blockIdx.y * TILE;
    const int b  = blockIdx.z;
    const int x = x0 + tx, y = y0 + ty;

    const float* mot_x = gt_motion + (size_t)b * 2 * HW;  // channel 0 -> ax
    const float* mot_y = mot_x + HW;                      // channel 1 -> ay
    const float* imP   = im_input + ((size_t)b * 6 + 3) * HW;  // last 3 channels

    // ---------------- phase 0: im halo -> REGISTERS (LDS write deferred) -------
    float2 imr01[2]; float imr2[2];
    #pragma unroll
    for (int k = 0; k < 2; k++) {
        int i = tid + k * 256;
        float2 v01 = make_float2(0.0f, 0.0f); float v2 = 0.0f;
        if (i < HH) {
            int hy = i / HALO, hx = i - hy * HALO;
            int gy = y0 - 3 + hy, gx = x0 - 3 + hx;
            if (gy >= 0 && gy < IMH && gx >= 0 && gx < IMW) {
                int off = gy * IMW + gx;
                v01.x = imP[off];
                v01.y = imP[off + HW];
                v2    = imP[off + 2 * HW];
            }
        }
        imr01[k] = v01; imr2[k] = v2;
    }

    // ---------------- phase 1: staging ----------------
    {   // KV: straight copy from precomputed ws table (b128 both sides)
        const uint4* kvsrc = (const uint4*)(ws + WS_KV);
        uint4*       kvdst = (uint4*)KV;
        for (int i = tid; i < 516; i += 256) kvdst[i] = kvsrc[i];
    }
    #pragma unroll
    for (int k = 0; k < 2; k++) {                       // packed motion halo
        int i = tid + k * 256;
        if (i < HH) {
            int hy = i / HALO, hx = i - hy * HALO;
            int gy = y0 - 3 + hy, gx = x0 - 3 + hx;
            unsigned pf = 0u, n4b = 255u;               // 255 = OOB sentinel
            if (gy >= 0 && gy < IMH && gx >= 0 && gx < IMW) {
                int off = gy * IMW + gx;
                float ay = mot_y[off] + 3.0f;
                float ax = mot_x[off] + 3.0f;
                float iyf = floorf(ay), ixf = floorf(ax);
                float fy = ay - iyf,    fx = ax - ixf;
                int n00 = (int)iyf * KK + (int)ixf;
                n00 = (n00 < 0) ? 0 : ((n00 > 40) ? 40 : n00);
                pf  = h2u(__halves2half2(__float2half_rn(fy), __float2half_rn(fx)));
                n4b = (unsigned)(n00 * 4);
            }
            haloF[i]  = pf;
            haloB8[i] = (unsigned char)n4b;
        }
    }
    {   // zero omV (10752 dwords) via b128
        uint4* p = reinterpret_cast<uint4*>(omV);
        for (int i = tid; i < (2 * NV * 128) / 4; i += 256) p[i] = make_uint4(0, 0, 0, 0);
    }

    __syncthreads();

    // ---------------- phase 2: m_mask dense write (exact f32) ----------------
    {
        int off = y * IMW + x;
        float ay = mot_y[off] + 3.0f;
        float ax = mot_x[off] + 3.0f;
        float iyf = floorf(ay), ixf = floorf(ax);
        float fy = ay - iyf,    fx = ax - ixf;
        int   iy = (int)iyf,    ix = (int)ixf;
        float wyA[KK], wxB[KK];
        #pragma unroll
        for (int a = 0; a < KK; a++) {
            wyA[a] = (a == iy) ? (1.0f - fy) : ((a == iy + 1) ? fy : 0.0f);
            wxB[a] = (a == ix) ? (1.0f - fx) : ((a == ix + 1) ? fx : 0.0f);
        }
        float* mm = out_mask + (size_t)b * NCLASS * HW + off;
        #pragma unroll
        for (int a = 0; a < KK; a++)
            #pragma unroll
            for (int bb = 0; bb < KK; bb++)
                mm[(size_t)(a * KK + bb) * HW] = wyA[a] * wxB[bb];
    }

    // ---------------- phase 3: scatter, row-batched, VOP3P op_sel core ---------
    // thread-private om column (px = tid&127, half = tid>>7): no collisions;
    // per-thread RMW ordering guaranteed by in-order DS issue.
    unsigned* const omHalf = omV + (tid >> 7) * (NV * 128) + (tid & 127);
    const unsigned c_m11 = 0x3C00BC00u;   // (lo=-1.0h, hi=+1.0h)
    const unsigned c_10  = 0x00003C00u;   // (lo=+1.0h, hi= 0.0h)
    #pragma unroll
    for (int u = 0; u < KK; u++) {
        unsigned pfr[KK], n4r[KK];
        #pragma unroll
        for (int v = 0; v < KK; v++) {                  // batch: expose read ILP
            int q = (ty + u) * HALO + (tx + v);
            pfr[v] = haloF[q];                          // ds_read2_b32-merged
            n4r[v] = (unsigned)haloB8[q];               // ds_read_u8
        }
        #pragma unroll
        for (int v = 0; v < KK; v++) {
            const int s = u * KK + v;                   // compile-time
            unsigned n4u = n4r[v];
            unsigned n4  = (n4u == 255u) ? 0u : n4u;
            unsigned wyb, wx2;
            // wy = (1-fy, fy) : one pk_fma, fy broadcast via op_sel
            asm("v_pk_fma_f16 %0, %1, %2, %3 op_sel:[0,0,0] op_sel_hi:[0,1,1]"
                : "=v"(wyb) : "v"(pfr[v]), "v"(c_m11), "v"(c_10));
            // wx2 = (1-fx, fx) : fx broadcast via op_sel
            asm("v_pk_fma_f16 %0, %1, %2, %3 op_sel:[1,0,0] op_sel_hi:[1,1,1]"
                : "=v"(wx2) : "v"(pfr[v]), "v"(c_m11), "v"(c_10));
            wyb = (n4u == 255u) ? 0u : wyb;             // OOB -> zero weights
            const unsigned* kp =
                (const unsigned*)((const char*)KV + s * (NV * 4) + n4);
            unsigned kvA = kp[0], kvB = kp[1];          // ds_read2_b32 (0,1)
            unsigned* ob = (unsigned*)((char*)omHalf + n4 * 128);  // n00*512 B
            unsigned o0 = ob[0], o1 = ob[128];          // ds_read2_b32 (0,128)
            unsigned tA, tB;
            // tA = wy * bcast_lo(wx2) = (w00, w10); tB = wy * bcast_hi = (w01, w11)
            asm("v_pk_mul_f16 %0, %1, %2 op_sel:[0,0] op_sel_hi:[1,0]"
                : "=v"(tA) : "v"(wyb), "v"(wx2));
            asm("v_pk_mul_f16 %0, %1, %2 op_sel:[0,1] op_sel_hi:[1,1]"
                : "=v"(tB) : "v"(wyb), "v"(wx2));
            __half2 cA = __hmul2(u2h(tA), u2h(kvA));
            __half2 cB = __hmul2(u2h(tB), u2h(kvB));
            ob[0]   = h2u(__hadd2(u2h(o0), cA));        // ds_write2_b32 (0,128)
            ob[128] = h2u(__hadd2(u2h(o1), cB));
        }
    }

    __syncthreads();   // omV complete; haloF/haloB/KV now dead

    // ---------------- phase 4 prologue: B fragments via 12 x b128 from ws ------
    uint4 braw[3][4];
    {
        const uint4* bsrc = (const uint4*)(ws + WS_B);
        #pragma unroll
        for (int kit = 0; kit < 3; kit++)
            #pragma unroll
            for (int nt = 0; nt < 4; nt++)
                braw[kit][nt] = bsrc[(kit * 4 + nt) * 64 + lane];
    }

    // ---------------- phase 3.5: im registers -> LDS (overlay dead region) -----
    #pragma unroll
    for (int k = 0; k < 2; k++) {
        int i = tid + k * 256;
        if (i < HH) { iml64[i] = imr01[k]; iml32[i] = imr2[k]; }
    }

    // ---------------- phase 4+5: K=96 MFMA GEMM, A = V dwords DIRECT -----------
    // W[px][t] = sum_v loV[v]*K[v][t] + hiV[v]*K[v+7][t]
    f32x4 acc[4][4];
    #pragma unroll
    for (int mt = 0; mt < 4; mt++)
        #pragma unroll
        for (int nt = 0; nt < 4; nt++)
            acc[mt][nt] = (f32x4){0.0f, 0.0f, 0.0f, 0.0f};

    const int vb0  = (lane >> 4) * 4;
    const int tcol = lane & 15;
    #pragma unroll
    for (int kit = 0; kit < 3; kit++) {
        f16x8 afk[4];
        #pragma unroll
        for (int mt = 0; mt < 4; mt++) {
            int px = wv_id * 64 + mt * 16 + tcol;
            const unsigned* pxb = omV + (px >> 7) * (NV * 128) + (px & 127);
            int vb = kit * 16 + vb0;
            union { unsigned u[4]; f16x8 v; } au;
            #pragma unroll
            for (int j = 0; j < 4; j++) {
                unsigned d = pxb[(vb + j) * 128];        // ds_read2-mergeable
                au.u[j] = (vb + j <= 41) ? d : 0u;       // mask garbage rows
            }
            afk[mt] = au.v;
        }
        #pragma unroll
        for (int mt = 0; mt < 4; mt++) {
            #pragma unroll
            for (int nt = 0; nt < 4; nt++) {
                union { uint4 q; f16x8 v; } bc; bc.q = braw[kit][nt];
                acc[mt][nt] = __builtin_amdgcn_mfma_f32_16x16x32_f16(afk[mt], bc.v, acc[mt][nt], 0, 0, 0);
            }
        }
    }

    __syncthreads();   // all omV reads done before W overwrites the region

    // ---------------- phase 5b: packed W write (16 x ds_write2_b32) ------------
    // C/D layout: col=lane&15 (t0), row=(lane>>4)*4+reg (px)
    // dword t0 of row px = (t0, t0+16); dword 16+t0 = (t0+32, t0+48)
    #pragma unroll
    for (int mt = 0; mt < 4; mt++) {
        #pragma unroll
        for (int r = 0; r < 4; r++) {
            int px = wv_id * 64 + mt * 16 + (lane >> 4) * 4 + r;
            unsigned* wrow = SH + px * WROW + tcol;
            unsigned v0 = h2u(__halves2half2(__float2half_rn(acc[mt][0][r]),
                                             __float2half_rn(acc[mt][1][r])));
            unsigned v1 = h2u(__halves2half2(__float2half_rn(acc[mt][2][r]),
                                             __float2half_rn(acc[mt][3][r])));
            wrow[0]  = v0;                               // ds_write2_b32 (0,16)
            wrow[16] = v1;
        }
    }

    __syncthreads();   // W complete; iml writes also ordered before here

    // ---------------- phase 6: apply effective 7x7 kernel ----------------------
    union { uint2 q[16]; unsigned d[32]; } wr;           // 16 x b64 (read2-merged)
    const uint2* wp = (const uint2*)(SH + tid * WROW);   // 136B stride, 8B aligned
    #pragma unroll
    for (int c = 0; c < 16; c++) wr.q[c] = wp[c];

    // static half extraction per t
    #define WHALF(t) ( (t) < 16 ? __low2half(u2h(wr.d[(t)])) :           \
                       (t) < 32 ? __high2half(u2h(wr.d[(t) - 16])) :     \
                       (t) < 48 ? __low2half(u2h(wr.d[(t) - 16])) :      \
                                  __high2half(u2h(wr.d[16])) )

    float a0 = 0.0f, a1 = 0.0f, a2 = 0.0f;
    #pragma unroll
    for (int p = 0; p < KK; p++) {
        #pragma unroll
        for (int qq = 0; qq < KK; qq++) {
            float wvv = __half2float(WHALF(p * KK + qq));
            int   hq  = (ty + p) * HALO + (tx + qq);
            float2 i01 = iml64[hq];                      // ds_read_b64
            float  i2  = iml32[hq];                      // ds_read_b32
            a0 = fmaf(wvv, i01.x, a0);
            a1 = fmaf(wvv, i01.y, a1);
            a2 = fmaf(wvv, i2,    a2);
        }
    }
    #undef WHALF
    float* pr = out_pred + (size_t)b * 3 * HW + y * IMW + x;
    pr[0]      = a0;
    pr[HW]     = a1;
    pr[2 * HW] = a2;
}

extern "C" void kernel_launch(void* const* d_in, const int* in_sizes, int n_in,
                              void* d_out, int out_size, void* d_ws, size_t ws_size,
                              hipStream_t stream) {
    const float* im_input  = (const float*)d_in[0];
    // d_in[1] = im_output: unused by the reference computation
    const float* gt_motion = (const float*)d_in[2];
    const float* m_kernel  = (const float*)d_in[3];

    float* pred = (float*)d_out;                        // (16,3,256,256)
    float* mask = pred + (size_t)16 * 3 * HW;           // (16,49,256,256)

    hipLaunchKernelGGL(gtnet_setup, dim3(1), dim3(256), 0, stream,
                       m_kernel, (unsigned*)d_ws);

    dim3 grid(IMW / TILE, IMH / TILE, 16);
    dim3 block(256);
    hipLaunchKernelGGL(gtnet_kernel, grid, block, 0, stream,
                       im_input, gt_motion, pred, mask, (const unsigned*)d_ws);
}